// Round 8
// baseline (180.697 us; speedup 1.0000x reference)
//
#include <hip/hip_runtime.h>
#include <stdint.h>

// fp32 inputs, FP32 outputs (established R7: harness reads np.float32):
// qps/kps: [256][32][8][64] f32 ; qpn/kpn: [256][8][8][64] f32
// d_out: float32, FIRST s_ps repeat-expanded [8][8][256][256] (4,194,304),
// THEN s_pn tiled [8][8][256][256] (4,194,304).
// S[b,h,l,s] = (1/8) * sum_e Q[b,l,h,e] K[b,s,h,e]; softmax over s;
// mean over ch (b = bo*32+ch, ch innermost).

// ONE kernel, NO workspace. grid = 128 blocks x 256 threads.
// blk <  64 : patch_size branch, a = blk = bo*8+h -> out0 slab (65,536 f32).
// blk >= 64 : patch_num branch,  a2 = blk-64      -> out1 slab (65,536 f32).
__global__ __launch_bounds__(256)
void fused_kernel(const float* __restrict__ qps,
                  const float* __restrict__ kps,
                  const float* __restrict__ qpn,
                  const float* __restrict__ kpn,
                  float* __restrict__ out)
{
    __shared__ float red[4][32 * 36];   // per-wave 32 rows (l) x 36 (s, +4 pad)
    __shared__ float fin[32 * 32];      // final channel-mean matrix [l][s]
    const int tid  = threadIdx.x;
    const int wv   = tid >> 6;
    const int lane = tid & 63;
    const int blk  = blockIdx.x;

    if (blk < 64) {
        // ---- patch_size: wave wv handles channels wv*8 .. wv*8+7 ----
        const int a  = blk;            // bo*8 + h
        const int bo = a >> 3, h = a & 7;
        const int i = lane >> 3, j = lane & 7;   // lane owns l=4i..4i+3, s=4j..4j+3

        float pa[4][4];
        #pragma unroll
        for (int r = 0; r < 4; ++r)
            #pragma unroll
            for (int c = 0; c < 4; ++c) pa[r][c] = 0.f;

        for (int cc = 0; cc < 8; ++cc) {
            const int b = bo * 32 + wv * 8 + cc;
            // float4 pointers; l -> l+1 stride = 8*64/4 = 128 float4
            const float4* Q = reinterpret_cast<const float4*>(qps) + ((b * 32 + 4 * i) * 8 + h) * 16;
            const float4* K = reinterpret_cast<const float4*>(kps) + ((b * 32 + 4 * j) * 8 + h) * 16;

            float acc[4][4];
            #pragma unroll
            for (int r = 0; r < 4; ++r)
                #pragma unroll
                for (int c = 0; c < 4; ++c) acc[r][c] = 0.f;

            #pragma unroll 4
            for (int c = 0; c < 16; ++c) {   // e-chunks of 4
                float4 q[4], k[4];
                #pragma unroll
                for (int r = 0; r < 4; ++r) { q[r] = Q[r * 128 + c]; k[r] = K[r * 128 + c]; }
                #pragma unroll
                for (int r = 0; r < 4; ++r)
                    #pragma unroll
                    for (int u = 0; u < 4; ++u) {
                        acc[r][u] = fmaf(q[r].x, k[u].x, acc[r][u]);
                        acc[r][u] = fmaf(q[r].y, k[u].y, acc[r][u]);
                        acc[r][u] = fmaf(q[r].z, k[u].z, acc[r][u]);
                        acc[r][u] = fmaf(q[r].w, k[u].w, acc[r][u]);
                    }
            }

            // softmax over s (own 4 + shfl across j bits 1,2,4) per row l=4i+r
            #pragma unroll
            for (int r = 0; r < 4; ++r) {
                float v0 = acc[r][0] * 0.125f, v1 = acc[r][1] * 0.125f;
                float v2 = acc[r][2] * 0.125f, v3 = acc[r][3] * 0.125f;
                float m = fmaxf(fmaxf(v0, v1), fmaxf(v2, v3));
                m = fmaxf(m, __shfl_xor(m, 1));
                m = fmaxf(m, __shfl_xor(m, 2));
                m = fmaxf(m, __shfl_xor(m, 4));
                float e0 = __expf(v0 - m), e1 = __expf(v1 - m);
                float e2 = __expf(v2 - m), e3 = __expf(v3 - m);
                float s = (e0 + e1) + (e2 + e3);
                s += __shfl_xor(s, 1);
                s += __shfl_xor(s, 2);
                s += __shfl_xor(s, 4);
                const float inv = 1.f / s;
                pa[r][0] += e0 * inv; pa[r][1] += e1 * inv;
                pa[r][2] += e2 * inv; pa[r][3] += e3 * inv;
            }
        }

        // stage per-wave 8-channel partials
        #pragma unroll
        for (int r = 0; r < 4; ++r) {
            float4 p; p.x = pa[r][0]; p.y = pa[r][1]; p.z = pa[r][2]; p.w = pa[r][3];
            *reinterpret_cast<float4*>(&red[wv][(4 * i + r) * 36 + 4 * j]) = p;
        }
        __syncthreads();

        // cross-wave reduce -> fin[l][s] (channel mean)
        {
            const int l = tid >> 3, s4 = (tid & 7) * 4;
            const float4 u0 = *reinterpret_cast<const float4*>(&red[0][l * 36 + s4]);
            const float4 u1 = *reinterpret_cast<const float4*>(&red[1][l * 36 + s4]);
            const float4 u2 = *reinterpret_cast<const float4*>(&red[2][l * 36 + s4]);
            const float4 u3 = *reinterpret_cast<const float4*>(&red[3][l * 36 + s4]);
            const float sc = 1.f / 32.f;
            float4 o;
            o.x = ((u0.x + u1.x) + (u2.x + u3.x)) * sc;
            o.y = ((u0.y + u1.y) + (u2.y + u3.y)) * sc;
            o.z = ((u0.z + u1.z) + (u2.z + u3.z)) * sc;
            o.w = ((u0.w + u1.w) + (u2.w + u3.w)) * sc;
            *reinterpret_cast<float4*>(&fin[tid * 4]) = o;   // fin[l*32+s]
        }
        __syncthreads();

        // write out0 slab (float32): out0[a][i][j] = fin[(i>>3)*32 + (j>>3)]
        // one float4 = 4 consecutive j (all in the same j>>3 bucket)
        float4* dst = reinterpret_cast<float4*>(out) + a * 16384;
        for (int n = 0; n < 64; ++n) {
            const int g = n * 256 + tid;          // 0..16383 float4s
            const int i2 = g >> 6;                // output row 0..255
            const int j4 = g & 63;                // j/4
            const float v = fin[(i2 >> 3) * 32 + (j4 >> 1)];
            float4 o; o.x = v; o.y = v; o.z = v; o.w = v;
            dst[g] = o;
        }
    } else {
        // ---- patch_num: 8x8 matrix; wave wv handles channels wv*8 .. wv*8+7 ----
        const int a2 = blk - 64;       // bo*8 + h
        const int bo = a2 >> 3, h = a2 & 7;
        const int i = lane >> 3, j = lane & 7;   // i = query l, j = key s

        float pacc = 0.f;
        for (int cc = 0; cc < 8; ++cc) {
            const int b = bo * 32 + wv * 8 + cc;
            const float4* qv = reinterpret_cast<const float4*>(qpn) + ((b * 8 + i) * 8 + h) * 16;
            const float4* kv = reinterpret_cast<const float4*>(kpn) + ((b * 8 + j) * 8 + h) * 16;

            float acc = 0.f;
            #pragma unroll
            for (int c = 0; c < 16; ++c) {
                float4 q = qv[c], k = kv[c];
                acc = fmaf(q.x, k.x, acc);
                acc = fmaf(q.y, k.y, acc);
                acc = fmaf(q.z, k.z, acc);
                acc = fmaf(q.w, k.w, acc);
            }
            const float s = acc * 0.125f;
            float m = s;
            m = fmaxf(m, __shfl_xor(m, 1));
            m = fmaxf(m, __shfl_xor(m, 2));
            m = fmaxf(m, __shfl_xor(m, 4));
            float e = __expf(s - m);
            float sum = e;
            sum += __shfl_xor(sum, 1);
            sum += __shfl_xor(sum, 2);
            sum += __shfl_xor(sum, 4);
            pacc += e / sum;
        }

        red[wv][lane] = pacc;
        __syncthreads();
        if (tid < 64) {
            // fin[l*8+s] for the 8x8 mean matrix
            fin[tid] = ((red[0][tid] + red[1][tid]) + (red[2][tid] + red[3][tid])) * (1.f / 32.f);
        }
        __syncthreads();

        // write out1 slab (float32): out1[a2][i][j] = fin[(i&7)*8 + (j&7)]
        // one float4 = 4 consecutive j = half a row of the 8x8 matrix
        float4* dst = reinterpret_cast<float4*>(out) + 1048576 + a2 * 16384;
        for (int n = 0; n < 64; ++n) {
            const int g = n * 256 + tid;          // 0..16383 float4s
            const int i2 = g >> 6;                // output row 0..255
            const int j4 = g & 63;                // j/4
            const float* row = &fin[(i2 & 7) * 8 + 4 * (j4 & 1)];
            float4 o; o.x = row[0]; o.y = row[1]; o.z = row[2]; o.w = row[3];
            dst[g] = o;
        }
    }
}

extern "C" void kernel_launch(void* const* d_in, const int* in_sizes, int n_in,
                              void* d_out, int out_size, void* d_ws, size_t ws_size,
                              hipStream_t stream) {
    // Size-scan input assignment (dict order: qps, kps, qpn, kpn)
    const float *qps = nullptr, *kps = nullptr, *qpn = nullptr, *kpn = nullptr;
    for (int idx = 0; idx < n_in; ++idx) {
        if (in_sizes[idx] == 256 * 32 * 8 * 64) {
            if (!qps) qps = (const float*)d_in[idx];
            else if (!kps) kps = (const float*)d_in[idx];
        } else if (in_sizes[idx] == 256 * 8 * 8 * 64) {
            if (!qpn) qpn = (const float*)d_in[idx];
            else if (!kpn) kpn = (const float*)d_in[idx];
        }
    }

    fused_kernel<<<128, 256, 0, stream>>>(qps, kps, qpn, kpn, (float*)d_out);
}

// Round 9
// 122.070 us; speedup vs baseline: 1.4803x; 1.4803x over previous
//
#include <hip/hip_runtime.h>
#include <stdint.h>

// fp32 inputs, fp32 outputs (established R8):
// qps/kps: [256][32][8][64] f32 ; qpn/kpn: [256][8][8][64] f32
// d_out: f32, FIRST s_ps repeat-expanded [8][8][256][256] (4,194,304 elems),
// THEN s_pn tiled [8][8][256][256].
// S[b,h,l,s] = (1/8)*sum_e Q[b,l,h,e]K[b,s,h,e]; softmax over s; mean over
// the 32 channels (b = bo*32+ch).

// Kernel 1: scores + softmax + channel-mean accumulation into ws.
// grid = 1024 x 256. blk < 512: patch_size (a = blk>>3, chunk = blk&7, wave
// wv owns channel chunk*4+wv). blk >= 512: patch_num, one (b,h) per wave.
__global__ __launch_bounds__(256)
void scores_kernel(const float* __restrict__ qps,
                   const float* __restrict__ kps,
                   const float* __restrict__ qpn,
                   const float* __restrict__ kpn,
                   float* __restrict__ ws_ps,   // [64][32][32] mean accum (zeroed)
                   float* __restrict__ ws_pn)   // [64][8][8]   mean accum (zeroed)
{
    __shared__ float red[4][32 * 36];   // per-wave 32 rows (l) x 36 (s, +4 pad)
    const int tid  = threadIdx.x;
    const int wv   = tid >> 6;
    const int lane = tid & 63;
    const int blk  = blockIdx.x;

    if (blk < 512) {
        // ---- patch_size: one wave = one (a, ch) 32x32 softmax ----
        const int a     = blk >> 3;    // bo*8 + h
        const int chunk = blk & 7;
        const int bo = a >> 3, h = a & 7;
        const int ch = chunk * 4 + wv;
        const int b  = bo * 32 + ch;
        const int i = lane >> 3, j = lane & 7;   // lane owns l=4i..4i+3, s=4j..4j+3

        const float4* Q = reinterpret_cast<const float4*>(qps) + ((b * 32 + 4 * i) * 8 + h) * 16;
        const float4* K = reinterpret_cast<const float4*>(kps) + ((b * 32 + 4 * j) * 8 + h) * 16;

        float acc[4][4];
        #pragma unroll
        for (int r = 0; r < 4; ++r)
            #pragma unroll
            for (int c = 0; c < 4; ++c) acc[r][c] = 0.f;

        #pragma unroll 4
        for (int c = 0; c < 16; ++c) {   // e-chunks of 4; row stride = 128 float4
            float4 q[4], k[4];
            #pragma unroll
            for (int r = 0; r < 4; ++r) { q[r] = Q[r * 128 + c]; k[r] = K[r * 128 + c]; }
            #pragma unroll
            for (int r = 0; r < 4; ++r)
                #pragma unroll
                for (int u = 0; u < 4; ++u) {
                    acc[r][u] = fmaf(q[r].x, k[u].x, acc[r][u]);
                    acc[r][u] = fmaf(q[r].y, k[u].y, acc[r][u]);
                    acc[r][u] = fmaf(q[r].z, k[u].z, acc[r][u]);
                    acc[r][u] = fmaf(q[r].w, k[u].w, acc[r][u]);
                }
        }

        // softmax over s (own 4 + shfl across j bits 1,2,4); fold 1/32 mean
        #pragma unroll
        for (int r = 0; r < 4; ++r) {
            float v0 = acc[r][0] * 0.125f, v1 = acc[r][1] * 0.125f;
            float v2 = acc[r][2] * 0.125f, v3 = acc[r][3] * 0.125f;
            float m = fmaxf(fmaxf(v0, v1), fmaxf(v2, v3));
            m = fmaxf(m, __shfl_xor(m, 1));
            m = fmaxf(m, __shfl_xor(m, 2));
            m = fmaxf(m, __shfl_xor(m, 4));
            float e0 = __expf(v0 - m), e1 = __expf(v1 - m);
            float e2 = __expf(v2 - m), e3 = __expf(v3 - m);
            float s = (e0 + e1) + (e2 + e3);
            s += __shfl_xor(s, 1);
            s += __shfl_xor(s, 2);
            s += __shfl_xor(s, 4);
            const float inv = 1.f / (s * 32.f);
            float4 p; p.x = e0 * inv; p.y = e1 * inv; p.z = e2 * inv; p.w = e3 * inv;
            *reinterpret_cast<float4*>(&red[wv][(4 * i + r) * 36 + 4 * j]) = p;
        }
        __syncthreads();

        // cross-wave reduce (4 channels) -> one float4 atomic add per thread
        const int l = tid >> 3, s4 = (tid & 7) * 4;
        const float4 u0 = *reinterpret_cast<const float4*>(&red[0][l * 36 + s4]);
        const float4 u1 = *reinterpret_cast<const float4*>(&red[1][l * 36 + s4]);
        const float4 u2 = *reinterpret_cast<const float4*>(&red[2][l * 36 + s4]);
        const float4 u3 = *reinterpret_cast<const float4*>(&red[3][l * 36 + s4]);
        float* dst = ws_ps + a * 1024 + tid * 4;
        unsafeAtomicAdd(dst + 0, (u0.x + u1.x) + (u2.x + u3.x));
        unsafeAtomicAdd(dst + 1, (u0.y + u1.y) + (u2.y + u3.y));
        unsafeAtomicAdd(dst + 2, (u0.z + u1.z) + (u2.z + u3.z));
        unsafeAtomicAdd(dst + 3, (u0.w + u1.w) + (u2.w + u3.w));
    } else {
        // ---- patch_num: one (b,h) per wave; lane = (l,s) cell of 8x8 ----
        const int pid = (blk - 512) * 4 + wv;   // 0..2047
        const int b = pid >> 3, h = pid & 7;
        const int i = lane >> 3, j = lane & 7;
        const float4* qv = reinterpret_cast<const float4*>(qpn) + ((b * 8 + i) * 8 + h) * 16;
        const float4* kv = reinterpret_cast<const float4*>(kpn) + ((b * 8 + j) * 8 + h) * 16;

        float acc = 0.f;
        #pragma unroll
        for (int c = 0; c < 16; ++c) {
            float4 q = qv[c], k = kv[c];
            acc = fmaf(q.x, k.x, acc);
            acc = fmaf(q.y, k.y, acc);
            acc = fmaf(q.z, k.z, acc);
            acc = fmaf(q.w, k.w, acc);
        }
        const float s = acc * 0.125f;
        float m = s;
        m = fmaxf(m, __shfl_xor(m, 1));
        m = fmaxf(m, __shfl_xor(m, 2));
        m = fmaxf(m, __shfl_xor(m, 4));
        float e = __expf(s - m);
        float sum = e;
        sum += __shfl_xor(sum, 1);
        sum += __shfl_xor(sum, 2);
        sum += __shfl_xor(sum, 4);
        unsafeAtomicAdd(ws_pn + ((b >> 5) * 8 + h) * 64 + lane, e / (sum * 32.f));
    }
}

// Kernel 2: expansion writer. 2,097,152 float4 stores (33.5 MB).
// grid = 8192 x 256; ws is L2-resident (272 KB).
__global__ __launch_bounds__(256)
void writer_kernel(const float* __restrict__ ws_ps,
                   const float* __restrict__ ws_pn,
                   float* __restrict__ out)
{
    const int g = blockIdx.x * 256 + threadIdx.x;   // float4 index
    float4* o4 = reinterpret_cast<float4*>(out);
    if (g < 1048576) {
        // out0[a][i][j] = ws_ps[a][i>>3][j>>3]; float4 = 4 j's, same bucket
        const int a  = g >> 14;
        const int r  = g & 16383;
        const int i  = r >> 6;
        const int j4 = r & 63;
        const float v = ws_ps[a * 1024 + (i >> 3) * 32 + (j4 >> 1)];
        float4 o; o.x = v; o.y = v; o.z = v; o.w = v;
        o4[g] = o;
    } else {
        // out1[a][i][j] = ws_pn[a][i&7][j&7]; float4 = half an 8-row
        const int g2 = g - 1048576;
        const int a  = g2 >> 14;
        const int r  = g2 & 16383;
        const int i  = r >> 6;
        const int j4 = r & 63;
        o4[g] = *reinterpret_cast<const float4*>(ws_pn + a * 64 + (i & 7) * 8 + 4 * (j4 & 1));
    }
}

extern "C" void kernel_launch(void* const* d_in, const int* in_sizes, int n_in,
                              void* d_out, int out_size, void* d_ws, size_t ws_size,
                              hipStream_t stream) {
    // Size-scan input assignment (dict order: qps, kps, qpn, kpn)
    const float *qps = nullptr, *kps = nullptr, *qpn = nullptr, *kpn = nullptr;
    for (int idx = 0; idx < n_in; ++idx) {
        if (in_sizes[idx] == 256 * 32 * 8 * 64) {
            if (!qps) qps = (const float*)d_in[idx];
            else if (!kps) kps = (const float*)d_in[idx];
        } else if (in_sizes[idx] == 256 * 8 * 8 * 64) {
            if (!qpn) qpn = (const float*)d_in[idx];
            else if (!kpn) kpn = (const float*)d_in[idx];
        }
    }

    float* ws_ps = (float*)d_ws;            // 64*1024 floats
    float* ws_pn = ws_ps + 64 * 1024;       // 64*64 floats

    hipMemsetAsync(d_ws, 0, (64 * 1024 + 64 * 64) * sizeof(float), stream);
    scores_kernel<<<1024, 256, 0, stream>>>(qps, kps, qpn, kpn, ws_ps, ws_pn);
    writer_kernel<<<8192, 256, 0, stream>>>(ws_ps, ws_pn, (float*)d_out);
}

// Round 10
// 120.837 us; speedup vs baseline: 1.4954x; 1.0102x over previous
//
#include <hip/hip_runtime.h>
#include <stdint.h>

// fp32 inputs, fp32 outputs (established R8):
// qps/kps: [256][32][8][64] f32 ; qpn/kpn: [256][8][8][64] f32
// d_out: f32, FIRST s_ps repeat-expanded [8][8][256][256] (4,194,304 elems),
// THEN s_pn tiled [8][8][256][256].
// S[b,h,l,s] = (1/8)*sum_e Q[b,l,h,e]K[b,s,h,e]; softmax over s; mean over
// the 32 channels (b = bo*32+ch).
//
// R10 structure: TWO dispatches, atomic-free, no memset.
//  scores: 1024 blocks. blk<512: patch_size block (a = blk>>3, chunk = blk&7),
//          wave wv owns channel chunk*4+wv; 4-wave LDS reduce -> plain store
//          of the 4-channel partial into ws_ps_part[a][chunk][1024].
//          blk>=512: patch_num block (a2, chunk) likewise ->
//          ws_pn_part[a2][chunk][64].
//  writer: sums the 8 chunk-partials per cell (L1/L2-broadcast reads) and
//          writes the expanded outputs with one float4 store per thread.

__global__ __launch_bounds__(256)
void scores_kernel(const float* __restrict__ qps,
                   const float* __restrict__ kps,
                   const float* __restrict__ qpn,
                   const float* __restrict__ kpn,
                   float* __restrict__ ws_ps,   // [64][8][1024] chunk partials
                   float* __restrict__ ws_pn)   // [64][8][64]   chunk partials
{
    __shared__ float red[4][32 * 36];   // per-wave 32 rows (l) x 36 (s, +4 pad)
    const int tid  = threadIdx.x;
    const int wv   = tid >> 6;
    const int lane = tid & 63;
    const int blk  = blockIdx.x;

    if (blk < 512) {
        // ---- patch_size: one wave = one (a, ch) 32x32 softmax ----
        const int a     = blk >> 3;    // bo*8 + h
        const int chunk = blk & 7;
        const int bo = a >> 3, h = a & 7;
        const int ch = chunk * 4 + wv;
        const int b  = bo * 32 + ch;
        const int i = lane >> 3, j = lane & 7;   // lane owns l=4i..4i+3, s=4j..4j+3

        const float4* Q = reinterpret_cast<const float4*>(qps) + ((b * 32 + 4 * i) * 8 + h) * 16;
        const float4* K = reinterpret_cast<const float4*>(kps) + ((b * 32 + 4 * j) * 8 + h) * 16;

        float acc[4][4];
        #pragma unroll
        for (int r = 0; r < 4; ++r)
            #pragma unroll
            for (int c = 0; c < 4; ++c) acc[r][c] = 0.f;

        #pragma unroll 4
        for (int c = 0; c < 16; ++c) {   // e-chunks of 4; row stride = 128 float4
            float4 q[4], k[4];
            #pragma unroll
            for (int r = 0; r < 4; ++r) { q[r] = Q[r * 128 + c]; k[r] = K[r * 128 + c]; }
            #pragma unroll
            for (int r = 0; r < 4; ++r)
                #pragma unroll
                for (int u = 0; u < 4; ++u) {
                    acc[r][u] = fmaf(q[r].x, k[u].x, acc[r][u]);
                    acc[r][u] = fmaf(q[r].y, k[u].y, acc[r][u]);
                    acc[r][u] = fmaf(q[r].z, k[u].z, acc[r][u]);
                    acc[r][u] = fmaf(q[r].w, k[u].w, acc[r][u]);
                }
        }

        // softmax over s (own 4 + shfl across j bits 1,2,4); fold 1/32 mean
        #pragma unroll
        for (int r = 0; r < 4; ++r) {
            float v0 = acc[r][0] * 0.125f, v1 = acc[r][1] * 0.125f;
            float v2 = acc[r][2] * 0.125f, v3 = acc[r][3] * 0.125f;
            float m = fmaxf(fmaxf(v0, v1), fmaxf(v2, v3));
            m = fmaxf(m, __shfl_xor(m, 1));
            m = fmaxf(m, __shfl_xor(m, 2));
            m = fmaxf(m, __shfl_xor(m, 4));
            float e0 = __expf(v0 - m), e1 = __expf(v1 - m);
            float e2 = __expf(v2 - m), e3 = __expf(v3 - m);
            float s = (e0 + e1) + (e2 + e3);
            s += __shfl_xor(s, 1);
            s += __shfl_xor(s, 2);
            s += __shfl_xor(s, 4);
            const float inv = 1.f / (s * 32.f);
            float4 p; p.x = e0 * inv; p.y = e1 * inv; p.z = e2 * inv; p.w = e3 * inv;
            *reinterpret_cast<float4*>(&red[wv][(4 * i + r) * 36 + 4 * j]) = p;
        }
        __syncthreads();

        // cross-wave reduce (4 channels) -> plain float4 store of the partial
        const int l = tid >> 3, s4 = (tid & 7) * 4;
        const float4 u0 = *reinterpret_cast<const float4*>(&red[0][l * 36 + s4]);
        const float4 u1 = *reinterpret_cast<const float4*>(&red[1][l * 36 + s4]);
        const float4 u2 = *reinterpret_cast<const float4*>(&red[2][l * 36 + s4]);
        const float4 u3 = *reinterpret_cast<const float4*>(&red[3][l * 36 + s4]);
        float4 o;
        o.x = (u0.x + u1.x) + (u2.x + u3.x);
        o.y = (u0.y + u1.y) + (u2.y + u3.y);
        o.z = (u0.z + u1.z) + (u2.z + u3.z);
        o.w = (u0.w + u1.w) + (u2.w + u3.w);
        reinterpret_cast<float4*>(ws_ps + (a * 8 + chunk) * 1024)[tid] = o;
    } else {
        // ---- patch_num: block (a2, chunk); wave wv = channel chunk*4+wv ----
        const int bb    = blk - 512;
        const int a2    = bb >> 3;     // bo*8 + h
        const int chunk = bb & 7;
        const int bo = a2 >> 3, h = a2 & 7;
        const int b  = bo * 32 + chunk * 4 + wv;
        const int i = lane >> 3, j = lane & 7;
        const float4* qv = reinterpret_cast<const float4*>(qpn) + ((b * 8 + i) * 8 + h) * 16;
        const float4* kv = reinterpret_cast<const float4*>(kpn) + ((b * 8 + j) * 8 + h) * 16;

        float acc = 0.f;
        #pragma unroll
        for (int c = 0; c < 16; ++c) {
            float4 q = qv[c], k = kv[c];
            acc = fmaf(q.x, k.x, acc);
            acc = fmaf(q.y, k.y, acc);
            acc = fmaf(q.z, k.z, acc);
            acc = fmaf(q.w, k.w, acc);
        }
        const float s = acc * 0.125f;
        float m = s;
        m = fmaxf(m, __shfl_xor(m, 1));
        m = fmaxf(m, __shfl_xor(m, 2));
        m = fmaxf(m, __shfl_xor(m, 4));
        float e = __expf(s - m);
        float sum = e;
        sum += __shfl_xor(sum, 1);
        sum += __shfl_xor(sum, 2);
        sum += __shfl_xor(sum, 4);

        red[wv][lane] = e / (sum * 32.f);
        __syncthreads();
        if (tid < 64) {
            ws_pn[(a2 * 8 + chunk) * 64 + tid] =
                (red[0][tid] + red[1][tid]) + (red[2][tid] + red[3][tid]);
        }
    }
}

// Writer: 8-way chunk-partial sum + expansion. 2,097,152 float4 stores.
__global__ __launch_bounds__(256)
void writer_kernel(const float* __restrict__ ws_ps,
                   const float* __restrict__ ws_pn,
                   float* __restrict__ out)
{
    const int g = blockIdx.x * 256 + threadIdx.x;   // float4 index
    float4* o4 = reinterpret_cast<float4*>(out);
    if (g < 1048576) {
        // out0[a][i][j] = sum_k ws_ps[a][k][(i>>3)*32 + (j>>3)]
        const int a  = g >> 14;
        const int r  = g & 16383;
        const int i  = r >> 6;
        const int j4 = r & 63;
        const float* base = ws_ps + a * 8192 + (i >> 3) * 32 + (j4 >> 1);
        float v = 0.f;
        #pragma unroll
        for (int k = 0; k < 8; ++k) v += base[k * 1024];
        float4 o; o.x = v; o.y = v; o.z = v; o.w = v;
        o4[g] = o;
    } else {
        // out1[a][i][j] = sum_k ws_pn[a][k][(i&7)*8 + (j&7)]
        const int g2 = g - 1048576;
        const int a  = g2 >> 14;
        const int r  = g2 & 16383;
        const int i  = r >> 6;
        const int j4 = r & 63;
        const float* base = ws_pn + a * 512 + (i & 7) * 8 + 4 * (j4 & 1);
        float4 v = {0.f, 0.f, 0.f, 0.f};
        #pragma unroll
        for (int k = 0; k < 8; ++k) {
            const float4 p = *reinterpret_cast<const float4*>(base + k * 64);
            v.x += p.x; v.y += p.y; v.z += p.z; v.w += p.w;
        }
        o4[g] = v;
    }
}

extern "C" void kernel_launch(void* const* d_in, const int* in_sizes, int n_in,
                              void* d_out, int out_size, void* d_ws, size_t ws_size,
                              hipStream_t stream) {
    // Size-scan input assignment (dict order: qps, kps, qpn, kpn)
    const float *qps = nullptr, *kps = nullptr, *qpn = nullptr, *kpn = nullptr;
    for (int idx = 0; idx < n_in; ++idx) {
        if (in_sizes[idx] == 256 * 32 * 8 * 64) {
            if (!qps) qps = (const float*)d_in[idx];
            else if (!kps) kps = (const float*)d_in[idx];
        } else if (in_sizes[idx] == 256 * 8 * 8 * 64) {
            if (!qpn) qpn = (const float*)d_in[idx];
            else if (!kpn) kpn = (const float*)d_in[idx];
        }
    }

    float* ws_ps = (float*)d_ws;            // 64*8*1024 floats (2 MB)
    float* ws_pn = ws_ps + 64 * 8 * 1024;   // 64*8*64 floats (128 KB)

    scores_kernel<<<1024, 256, 0, stream>>>(qps, kps, qpn, kpn, ws_ps, ws_pn);
    writer_kernel<<<8192, 256, 0, stream>>>(ws_ps, ws_pn, (float*)d_out);
}